// Round 10
// baseline (639.326 us; speedup 1.0000x reference)
//
#include <hip/hip_runtime.h>

// QuantumQLSTM on MI355X — R21: single-barrier, in-wave-matvec rec.
// 4 waves / 256 threads, lane==h. Every wave redundantly computes ALL 12
// matvec columns from one ds_read_b128 of Hv (wsum + v_readlane->SGPR
// broadcast — zh never touches LDS). Each lane computes all 4 gates for its
// own h (no half-split, no exchange). ONE lds_barrier per step.
//
// R20 post-mortem (null): wide trans ops are FREE (removing 12/thread = +3us);
// only serial-chain segments pay (R14 −15, R19 −18). R21 removes from the
// chain: zh LDS roundtrip (~120cy), 2nd barrier (~100cy), gate exchange —
// at the cost of redundant (wide, free) per-wave matvec.
// Predicted: rec 324 -> 150-230us, total ~400-490. FETCH back to 4.1MB
// (zx reverts to R19 angle format). absmax ~unchanged (reassociation only).
//
// History: R1 4250 -> ... -> R11 632 (rec 354) -> R13 643 (NEUTRAL) ->
// R14 600 (rec 339) -> R16 600 (nt null) -> R18 891 (fusion REGRESSION) ->
// R19 578.6 (rec 321) -> R20 581.7 (rec 324, trans-removal NULL) -> R21.

#define T_DIM 512
#define B_DIM 256
#define D_DIM 256
#define H_DIM 256
#define DH    512   // D + H
#define NG    16    // 4 gates * NQ(4)
#define XPAD  68    // Xc/Wc LDS row stride (floats): 16B-aligned, 2-way max
#define INV2PI 0.15915494309189535f

typedef float f32x4 __attribute__((ext_vector_type(4)));  // clang-native 16B vec

#if __has_builtin(__builtin_amdgcn_fractf) && __has_builtin(__builtin_amdgcn_cosf)
#define TRIG_REV 1
#else
#define TRIG_REV 0
#endif

__device__ __forceinline__ float fast_sigmoid(float x) {
    return 1.0f / (1.0f + __expf(-x));
}
__device__ __forceinline__ float fast_tanh(float x) {
    // |x| <= ~2.1 here (|C| <= 0.557/(1-0.731)); exp safe
    float e = __expf(2.0f * x);
    return (e - 1.0f) / (e + 1.0f);
}
// cos(2*pi*x), x in revolutions (v_fract + v_cos; verified R19)
__device__ __forceinline__ float cos_rev(float x) {
#if TRIG_REV
    return __builtin_amdgcn_cosf(__builtin_amdgcn_fractf(x));
#else
    return __cosf(x * 6.283185307179586f);
#endif
}
// x + dpp_mov(x): one reduction level, VALU pipe.
template <int CTRL, int RM, int BM, bool BC>
__device__ __forceinline__ float dadd(float x) {
    return x + __int_as_float(
        __builtin_amdgcn_update_dpp(0, __float_as_int(x), CTRL, RM, BM, BC));
}
// full-wave sum; result valid in lane 63 (verified since R11)
__device__ __forceinline__ float wsum(float x) {
    x = dadd<0x111, 0xf, 0xf, true >(x);   // row_shr:1
    x = dadd<0x112, 0xf, 0xf, true >(x);   // row_shr:2
    x = dadd<0x114, 0xf, 0xf, true >(x);   // row_shr:4
    x = dadd<0x118, 0xf, 0xf, true >(x);   // row_shr:8
    x = dadd<0x142, 0xa, 0xf, false>(x);   // row_bcast:15
    x = dadd<0x143, 0xc, 0xf, false>(x);   // row_bcast:31 -> lane63
    return x;
}
// lane63 value -> wave-uniform SGPR broadcast
__device__ __forceinline__ float bcast63(float x) {
    return __int_as_float(__builtin_amdgcn_readlane(__float_as_int(x), 63));
}
// Barrier draining ONLY the LDS pipe (no vmcnt): global ops float across steps.
__device__ __forceinline__ void lds_barrier() {
    __asm__ volatile("s_waitcnt lgkmcnt(0)\n\ts_barrier" ::: "memory");
}

// -------------------- zx precompute (R19 verified: angles in REVOLUTIONS,
// zx = (b_q + phi_q + x.Wx[q,:]) / 2pi; 4x4 register tiling)
__global__ __launch_bounds__(256) void zx_kernel(
    const float* __restrict__ x,
    const float* __restrict__ Wf, const float* __restrict__ Wi,
    const float* __restrict__ Wu, const float* __restrict__ Wo,
    const float* __restrict__ bf, const float* __restrict__ bi,
    const float* __restrict__ bu, const float* __restrict__ bo,
    const float* __restrict__ phf, const float* __restrict__ phi,
    const float* __restrict__ phu, const float* __restrict__ pho,
    float* __restrict__ zx)
{
    __shared__ float Xc[256][XPAD];
    __shared__ float Wc[NG][XPAD];
    const int tid = threadIdx.x;
    const int rt  = tid >> 2;           // 0..63
    const int qt  = tid & 3;            // gate index 0..3

    const float* bv = (qt == 0) ? bf : (qt == 1) ? bi : (qt == 2) ? bu : bo;
    const float* pv = (qt == 0) ? phf : (qt == 1) ? phi : (qt == 2) ? phu : pho;
    float acc[4][4];
    #pragma unroll
    for (int j = 0; j < 4; ++j) {
        const float bj = bv[j] + pv[j];
        acc[0][j] = bj; acc[1][j] = bj; acc[2][j] = bj; acc[3][j] = bj;
    }

    const long base = (long)blockIdx.x * 256 * D_DIM;

    for (int c = 0; c < 4; ++c) {                 // k-chunk of 64
        const int k0 = c * 64;
        #pragma unroll
        for (int it = 0; it < 16; ++it) {
            const int e = tid + it * 256;
            const int row = e >> 4, col4 = (e & 15) * 4;
            *(float4*)&Xc[row][col4] =
                *(const float4*)(x + base + (long)row * D_DIM + k0 + col4);
        }
        {
            const int q16 = tid >> 4, col4 = (tid & 15) * 4;
            const int g = q16 >> 2, qj = q16 & 3;
            const float* W = (g == 0) ? Wf : (g == 1) ? Wi : (g == 2) ? Wu : Wo;
            *(float4*)&Wc[q16][col4] = *(const float4*)(W + qj * DH + k0 + col4);
        }
        __syncthreads();

        #pragma unroll 4
        for (int kk = 0; kk < 16; ++kk) {
            const int k4 = kk * 4;
            float4 xv0 = *(float4*)&Xc[rt][k4];
            float4 xv1 = *(float4*)&Xc[rt +  64][k4];
            float4 xv2 = *(float4*)&Xc[rt + 128][k4];
            float4 xv3 = *(float4*)&Xc[rt + 192][k4];
            float4 wv0 = *(float4*)&Wc[4 * qt + 0][k4];
            float4 wv1 = *(float4*)&Wc[4 * qt + 1][k4];
            float4 wv2 = *(float4*)&Wc[4 * qt + 2][k4];
            float4 wv3 = *(float4*)&Wc[4 * qt + 3][k4];
            #pragma unroll
            for (int i = 0; i < 4; ++i) {
                const float4 xv = (i == 0) ? xv0 : (i == 1) ? xv1 : (i == 2) ? xv2 : xv3;
                acc[i][0] = fmaf(xv.x, wv0.x, fmaf(xv.y, wv0.y, fmaf(xv.z, wv0.z, fmaf(xv.w, wv0.w, acc[i][0]))));
                acc[i][1] = fmaf(xv.x, wv1.x, fmaf(xv.y, wv1.y, fmaf(xv.z, wv1.z, fmaf(xv.w, wv1.w, acc[i][1]))));
                acc[i][2] = fmaf(xv.x, wv2.x, fmaf(xv.y, wv2.y, fmaf(xv.z, wv2.z, fmaf(xv.w, wv2.w, acc[i][2]))));
                acc[i][3] = fmaf(xv.x, wv3.x, fmaf(xv.y, wv3.y, fmaf(xv.z, wv3.z, fmaf(xv.w, wv3.w, acc[i][3]))));
            }
        }
        __syncthreads();
    }

    const long orow = (long)blockIdx.x * 256;
    #pragma unroll
    for (int i = 0; i < 4; ++i) {
        *(float4*)&zx[(orow + rt + 64 * i) * NG + qt * 4] =
            make_float4(acc[i][0] * INV2PI, acc[i][1] * INV2PI,
                        acc[i][2] * INV2PI, acc[i][3] * INV2PI);
    }
}

// -------------------- sequential core: ONE block, 256 threads (4 waves)
// lane==h ownership; per-wave redundant full matvec; zh via readlane SGPRs.
__global__ __launch_bounds__(256) void rec_kernel(
    const float* __restrict__ Wf, const float* __restrict__ Wi,
    const float* __restrict__ Wu, const float* __restrict__ Wo,
    const float* __restrict__ zx,
    float* __restrict__ hv_tab,   // [T][H]; hv_tab[-H..-1] is a scratch pad row
    float* __restrict__ c_fin)    // [H]
{
    __shared__ float Hbuf[2][H_DIM];       // double-buffered Hv
    const int tid  = threadIdx.x;          // 0..255 == h
    const int lane = tid & 63;
    const int h    = tid;

    // 12 recurrent columns, 4 weights each (this lane's Hv slice), revolutions
    float4 W[12];
    #pragma unroll
    for (int c = 0; c < 12; ++c) {
        const int g = c / 3, j = c % 3 + 1;
        const float* Wg = (g == 0) ? Wf : (g == 1) ? Wi : (g == 2) ? Wu : Wo;
        float4 w = *(const float4*)(Wg + j * DH + 256 + 4 * lane);
        w.x *= INV2PI; w.y *= INV2PI; w.z *= INV2PI; w.w *= INV2PI;
        W[c] = w;
    }

    float C = 0.0f, Hprev = 0.0f;
    Hbuf[1][tid] = 0.0f;                   // Hv[-1] = 0
    __syncthreads();

    // zx angle register double-buffer (depth 2): 4 float4 per t (16 q)
    float4 za0, za1, za2, za3, zb0, zb1, zb2, zb3;
    {
        const float4* p0 = (const float4*)(zx + (long)h * NG);
        const float4* p1 = (const float4*)(zx + ((long)B_DIM + h) * NG);
        za0 = p0[0]; za1 = p0[1]; za2 = p0[2]; za3 = p0[3];
        zb0 = p1[0]; zb1 = p1[1]; zb2 = p1[2]; zb3 = p1[3];
    }

    auto step = [&](int t, float4& z0, float4& z1, float4& z2, float4& z3) {
        // ---- longest-latency first: Hv[t-1] slice (this wave covers all 256)
        const float4 Hv4 = *(const float4*)&Hbuf[(t + 1) & 1][4 * lane];
        // early-issue global store of Hv[t-1] (floats across the step)
        hv_tab[(long)(t - 1) * H_DIM + h] = Hprev;

        // ---- in-wave matvec: 12 columns x dot4, then wave-sum + SGPR bcast
        float p[12];
        #pragma unroll
        for (int c = 0; c < 12; ++c)
            p[c] = fmaf(W[c].x, Hv4.x, fmaf(W[c].y, Hv4.y,
                       fmaf(W[c].z, Hv4.z, W[c].w * Hv4.w)));
        float zh[12];
        #pragma unroll
        for (int c = 0; c < 12; ++c) zh[c] = bcast63(wsum(p[c]));

        // ---- prefetch zx[t+2] into temps (independent; commit after gates)
        float4 n0, n1, n2, n3;
        {
            const int tp = (t + 2 < T_DIM) ? (t + 2) : t;
            const float4* pp = (const float4*)(zx + ((long)tp * B_DIM + h) * NG);
            n0 = pp[0]; n1 = pp[1]; n2 = pp[2]; n3 = pp[3];
        }

        // ---- all 4 gates for own h (wide; z*.y/z/w are wires 1..3)
        const float f_ = fast_sigmoid(cos_rev(z0.y + zh[0]) * cos_rev(z0.z + zh[1])  * cos_rev(z0.w + zh[2]));
        const float i_ = fast_sigmoid(cos_rev(z1.y + zh[3]) * cos_rev(z1.z + zh[4])  * cos_rev(z1.w + zh[5]));
        const float g_ = fast_tanh   (cos_rev(z2.y + zh[6]) * cos_rev(z2.z + zh[7])  * cos_rev(z2.w + zh[8]));
        const float o_ = fast_sigmoid(cos_rev(z3.y + zh[9]) * cos_rev(z3.z + zh[10]) * cos_rev(z3.w + zh[11]));

        C = fmaf(f_, C, i_ * g_);
        const float Hnew = o_ * fast_tanh(C);
        Hbuf[t & 1][h] = Hnew;
        Hprev = Hnew;
        z0 = n0; z1 = n1; z2 = n2; z3 = n3;
        lds_barrier();                     // the ONLY barrier per step
    };

    for (int t = 0; t < T_DIM; t += 2) {
        step(t,     za0, za1, za2, za3);
        step(t + 1, zb0, zb1, zb2, zb3);
    }

    hv_tab[(long)(T_DIM - 1) * H_DIM + h] = Hprev;
    c_fin[h] = C;
}

// -------------------- broadcast: out[t,b,:] = Hv[t,:]; tails hx=Hv[511], cx=Cfin
__global__ __launch_bounds__(256) void bc_kernel(
    const float* __restrict__ hv_tab, const float* __restrict__ c_fin,
    float* __restrict__ out)
{
    const int blk  = blockIdx.x;
    const int w    = threadIdx.x >> 6;
    const int lane = threadIdx.x & 63;

    const float* src;
    long base;
    int rbase;
    if (blk < 4 * T_DIM) {
        const int t = blk >> 2;
        rbase = (blk & 3) * 64;
        src = hv_tab + (long)t * H_DIM;
        base = (long)t * (B_DIM * H_DIM);
    } else {
        const int k = blk - 4 * T_DIM;        // 0..7
        rbase = (k & 3) * 64;
        src = (k < 4) ? (hv_tab + (long)(T_DIM - 1) * H_DIM) : c_fin;
        base = (long)T_DIM * (B_DIM * H_DIM) + (k < 4 ? 0 : (long)B_DIM * H_DIM);
    }
    const f32x4 v = ((const f32x4*)src)[lane];
    #pragma unroll
    for (int it = 0; it < 16; ++it) {
        const int row = rbase + w + 4 * it;
        __builtin_nontemporal_store(
            v, (f32x4*)(out + base + (long)row * H_DIM) + lane);
    }
}

extern "C" void kernel_launch(void* const* d_in, const int* in_sizes, int n_in,
                              void* d_out, int out_size, void* d_ws, size_t ws_size,
                              hipStream_t stream) {
    (void)in_sizes; (void)n_in; (void)out_size; (void)ws_size;
    const float* x   = (const float*)d_in[0];
    const float* Wf  = (const float*)d_in[1];
    const float* bf  = (const float*)d_in[2];
    const float* phf = (const float*)d_in[3];
    const float* Wi  = (const float*)d_in[4];
    const float* bi  = (const float*)d_in[5];
    const float* phi = (const float*)d_in[6];
    const float* Wu  = (const float*)d_in[7];
    const float* bu  = (const float*)d_in[8];
    const float* phu = (const float*)d_in[9];
    const float* Wo  = (const float*)d_in[10];
    const float* bo  = (const float*)d_in[11];
    const float* pho = (const float*)d_in[12];

    float* zx     = (float*)d_ws;                          // T*B*16 f = 8.39 MB
    float* hv_pad = zx + (size_t)T_DIM * B_DIM * NG;       // 256 f scratch (t=0 store)
    float* hv_tab = hv_pad + H_DIM;                        // T*H f = 512 KB
    float* c_fin  = hv_tab + (size_t)T_DIM * H_DIM;        // H f = 1 KB

    zx_kernel<<<T_DIM, 256, 0, stream>>>(
        x, Wf, Wi, Wu, Wo, bf, bi, bu, bo, phf, phi, phu, pho, zx);

    rec_kernel<<<1, 256, 0, stream>>>(
        Wf, Wi, Wu, Wo, zx, hv_tab, c_fin);

    bc_kernel<<<4 * T_DIM + 8, 256, 0, stream>>>(hv_tab, c_fin, (float*)d_out);
}